// Round 14
// baseline (58.995 us; speedup 1.0000x reference)
//
#include <hip/hip_runtime.h>
#include <stdint.h>

typedef unsigned short u16;
typedef unsigned int u32;
typedef __bf16 bf16x8 __attribute__((ext_vector_type(8)));
typedef float f32x4 __attribute__((ext_vector_type(4)));

#define MFMA16 __builtin_amdgcn_mfma_f32_16x16x32_bf16

// ---------------- helpers ----------------

__device__ __forceinline__ u16 f2bf(float f) {
    u32 u = __builtin_bit_cast(u32, f);
    u32 r = (u + 0x7FFFu + ((u >> 16) & 1u)) >> 16;
    return (u16)r;
}

__device__ __forceinline__ void gload_lds16(const u16* g, u16* l) {
    __builtin_amdgcn_global_load_lds(
        (const __attribute__((address_space(1))) void*)g,
        (__attribute__((address_space(3))) void*)l,
        16, 0, 0);
}

// ================= kernel 1: prep_w (standalone, tiny) =================
// Wt[o*4+s][i] (bf16 [4096][1024]) = sum_{q,r} c0[b,w,q,s]*c1[q,c,x,r,s]*c2[r,d,y,s]
// i=(b*128+c*8+d), o=(w*128+x*8+y); 512 blocks = (bc=128)x(part=4).

__global__ __launch_bounds__(256) void prep_w_kernel(const float* __restrict__ c0,
                                                     const float* __restrict__ c1,
                                                     const float* __restrict__ c2,
                                                     u16* __restrict__ Wt) {
    __shared__ float smem[10496];   // 41 KB: c0(256) c1(4096) c2(2048) w1(4096)
    const int t = threadIdx.x;

    float* l_c0 = smem;           // [w][q][s]     (slice at fixed b)
    float* l_c1 = smem + 256;     // [q][x][r][s]  (slice at fixed c)
    float* l_c2 = smem + 4352;    // [r][d][y][s]  (full)
    float* l_w1 = smem + 6400;    // [w][x][r][s]

    const int bid = blockIdx.x;
    const int bc = bid >> 2;      // 0..127
    const int part = bid & 3;     // 0..3 : w-pair {2p, 2p+1}
    const int b = bc >> 4, c = bc & 15;

    l_c0[t] = c0[b * 256 + t];
#pragma unroll
    for (int q = 0; q < 8; ++q) {
        l_c1[q * 512 + t]       = c1[(q * 16 + c) * 512 + t];
        l_c1[q * 512 + t + 256] = c1[(q * 16 + c) * 512 + t + 256];
    }
#pragma unroll
    for (int j = 0; j < 8; ++j) l_c2[t + 256 * j] = c2[t + 256 * j];
    __syncthreads();

    // W1[w][x][r][s] = sum_q c0[w,q,s] * c1[q,x,r,s]   (only w in {2p,2p+1})
#pragma unroll
    for (int j = 0; j < 4; ++j) {
        int idx = t + 256 * (part * 4 + j);   // ((w*16+x)*8+r)*4+s
        int s = idx & 3;
        int r = (idx >> 2) & 7;
        int xx = (idx >> 5) & 15;
        int w = idx >> 9;
        float acc = 0.f;
#pragma unroll
        for (int q = 0; q < 8; ++q)
            acc += l_c0[(w * 8 + q) * 4 + s] * l_c1[q * 512 + (xx * 8 + r) * 4 + s];
        l_w1[idx] = acc;
    }
    __syncthreads();

    // Wt[(o*4+s)][b*128+c*8+d] = sum_r W1[w,x,r,s] * c2[r,d,y,s]
#pragma unroll
    for (int j = 0; j < 4; ++j) {
        int idx = t + 256 * (part * 4 + j);   // ((w*16+x)*8+y)*4+s == o*4+s
        int s = idx & 3;
        int y = (idx >> 2) & 7;
        int xx = (idx >> 5) & 15;
        int w = idx >> 9;
        float acc[8] = {0.f, 0.f, 0.f, 0.f, 0.f, 0.f, 0.f, 0.f};
#pragma unroll
        for (int r = 0; r < 8; ++r) {
            float w1 = l_w1[((w * 16 + xx) * 8 + r) * 4 + s];
#pragma unroll
            for (int d = 0; d < 8; ++d)
                acc[d] += w1 * l_c2[((r * 8 + d) * 8 + y) * 4 + s];
        }
        uint4 pk;
        pk.x = (u32)f2bf(acc[0]) | ((u32)f2bf(acc[1]) << 16);
        pk.y = (u32)f2bf(acc[2]) | ((u32)f2bf(acc[3]) << 16);
        pk.z = (u32)f2bf(acc[4]) | ((u32)f2bf(acc[5]) << 16);
        pk.w = (u32)f2bf(acc[6]) | ((u32)f2bf(acc[7]) << 16);
        *reinterpret_cast<uint4*>(&Wt[(size_t)idx * 1024 + b * 128 + c * 8]) = pk;
    }
}

// ========== kernel 2: 256x256 GEMM with FUSED fp32->bf16 A-staging ==========
// C[M][N] = cvt_bf16(X[M][K]) * Wt[N][K]^T.  X fp32, Wt bf16.
// 512 threads = 8 waves (2M x 4N); per-wave 128x64 = acc[8][4] 16x16 frags.
// K-tile BK=64; 2 dbuf slots each for A and B (128 KiB LDS).
//
// A-path: register-staged directly from fp32 x -- load 2 float4 per unit,
// cast to bf16 (v_cvt_pk_bf16_f32, RNE), ds_write_b128 into the IDENTICAL
// swizzled LDS layout the read path already uses. Eliminates the conv
// kernel, the 25 MB xb round-trip, and one launch gap.
// B-path: unchanged gload_lds DMA with pre-swizzled source.
//
// Sync: minimal (R9-form, measured == counted vmcnt): boundary __syncthreads
// per K-tile (drains lgkm for ds_write visibility + vmcnt for B DMA).
//
// LDS layout (both A and B): row r (64 u16 = 128 B), 16B-chunk phys =
// logical ^ (r&7); frag reads at koff = ((ln>>4) [+4] ^ (ln&7))*8.
// XCD swizzle (T1, bijective, grid 256 = 16x16).

#define SLOT_U16 16384   // one slot: 256 rows * 64 u16 = 32 KB

__global__ __launch_bounds__(512, 2) void gemm256_kernel(const float* __restrict__ X,
                                                         const u16* __restrict__ B,
                                                         float* __restrict__ C,
                                                         int M, int N, int K) {
    __shared__ u16 As[2 * SLOT_U16];  // 64 KB
    __shared__ u16 Bs[2 * SLOT_U16];  // 64 KB

    const int t   = threadIdx.x;
    const int ln  = t & 63;
    const int wid = t >> 6;          // 0..7
    const int wr  = wid >> 2;        // 0..1 -> M offset wr*128
    const int wc  = wid & 3;         // 0..3 -> N offset wc*64

    // ---- XCD-aware bijective block swizzle (grid 256 = 16 x 16) ----
    const int bid = blockIdx.x;
    const int xcd = bid & 7;
    const int r8  = bid >> 3;            // 0..31
    const int bx  = (xcd & 1) * 8 + (r8 & 7);
    const int by  = (xcd >> 1) * 4 + (r8 >> 3);
    const int m0  = by * 256;
    const int n0  = bx * 256;
    const int NT  = K >> 6;          // 16 K-tiles

    // ---- fragment addressing (read path, unchanged from R12) ----
    const int frow  = ln & 15;
    const int koff0 = (((ln >> 4)    ) ^ (ln & 7)) * 8;   // kk=0 chunk (u16)
    const int koff1 = (((ln >> 4) + 4) ^ (ln & 7)) * 8;   // kk=1 chunk
    const int arow0 = (wr * 128 + frow) * 64;             // + fm*1024
    const int brow0 = (wc * 64  + frow) * 64;             // + fn*1024

    // ---- B staging (DMA): thread t -> row t>>3, phys chunk t&7,
    //      logical chunk (t&7)^((t>>3)&7), linear LDS dest t*16B.
    const int srow = t >> 3;
    const int scol = ((t & 7) ^ (srow & 7)) * 8;
    const u16* Bsrc = B + (size_t)(n0 + srow) * K + scol;

    // ---- A staging (reg + cvt + ds_write): unit j covers row srow + 64j,
    //      same logical chunk, LDS dest (row*8 + (t&7))*16B -> same layout.
    const float* Xsrc = X + (size_t)(m0 + srow) * K + scol;  // f32 elements
    const int awst = srow * 64 + (t & 7) * 8;                // u16 offset; +4096*j

    f32x4 acc[8][4] = {};

#define STG_B(H, L, KC, DST)                                                 \
    gload_lds16(Bsrc + (size_t)((H) * 128 + (L) * 64) * K + (KC),            \
                (DST) + (H) * 8192 + (L) * 4096 + t * 8);

#define A_LOAD(J, KC)                                                        \
    av##J##a = *reinterpret_cast<const float4*>(Xsrc + (size_t)(64 * (J)) * K + (KC)); \
    av##J##b = *reinterpret_cast<const float4*>(Xsrc + (size_t)(64 * (J)) * K + (KC) + 4);

#define A_WRITE(J, DST)                                                      \
    {   bf16x8 pk;                                                           \
        pk[0] = (__bf16)av##J##a.x; pk[1] = (__bf16)av##J##a.y;              \
        pk[2] = (__bf16)av##J##a.z; pk[3] = (__bf16)av##J##a.w;              \
        pk[4] = (__bf16)av##J##b.x; pk[5] = (__bf16)av##J##b.y;              \
        pk[6] = (__bf16)av##J##b.z; pk[7] = (__bf16)av##J##b.w;              \
        *reinterpret_cast<bf16x8*>((DST) + awst + 4096 * (J)) = pk;   }

#define READ_A(PH)                                                           \
    a0k0 = *(const bf16x8*)(Ab + arow0 + (2 * (PH)) * 1024 + koff0);         \
    a0k1 = *(const bf16x8*)(Ab + arow0 + (2 * (PH)) * 1024 + koff1);         \
    a1k0 = *(const bf16x8*)(Ab + arow0 + (2 * (PH) + 1) * 1024 + koff0);     \
    a1k1 = *(const bf16x8*)(Ab + arow0 + (2 * (PH) + 1) * 1024 + koff1);

#define MFMA_PH(PH)                                                          \
    _Pragma("unroll")                                                        \
    for (int n = 0; n < 4; ++n) {                                            \
        acc[2*(PH)][n]   = MFMA16(a0k0, bf[n][0], acc[2*(PH)][n],   0,0,0);  \
        acc[2*(PH)][n]   = MFMA16(a0k1, bf[n][1], acc[2*(PH)][n],   0,0,0);  \
        acc[2*(PH)+1][n] = MFMA16(a1k0, bf[n][0], acc[2*(PH)+1][n], 0,0,0);  \
        acc[2*(PH)+1][n] = MFMA16(a1k1, bf[n][1], acc[2*(PH)+1][n], 0,0,0);  \
    }

    float4 av0a, av0b, av1a, av1b, av2a, av2b, av3a, av3b;

    // ---- prologue: stage tile 0 (B via DMA, A via reg+cvt), drain ----
    STG_B(0, 0, 0, Bs) STG_B(0, 1, 0, Bs) STG_B(1, 0, 0, Bs) STG_B(1, 1, 0, Bs)
    A_LOAD(0, 0) A_LOAD(1, 0) A_LOAD(2, 0) A_LOAD(3, 0)
    A_WRITE(0, As) A_WRITE(1, As) A_WRITE(2, As) A_WRITE(3, As)
    __syncthreads();

    for (int kt = 0; kt < NT; ++kt) {
        const u16* Ab = As + (kt & 1) * SLOT_U16;
        const u16* Bb = Bs + (kt & 1) * SLOT_U16;
        u16* An = As + ((kt + 1) & 1) * SLOT_U16;
        u16* Bn = Bs + ((kt + 1) & 1) * SLOT_U16;
        const bool pf = (kt + 1) < NT;
        const int kc = (kt + 1) * 64;

        bf16x8 bf[4][2];
        bf16x8 a0k0, a0k1, a1k0, a1k1;

        // ---- tile top: issue next tile's B DMA + first half of A loads ----
        if (pf) {
            STG_B(0, 0, kc, Bn) STG_B(0, 1, kc, Bn)
            STG_B(1, 0, kc, Bn) STG_B(1, 1, kc, Bn)
            A_LOAD(0, kc) A_LOAD(1, kc)
        }

        // ---- compute phases 0-1 (B frags + A fm0..3) ----
#pragma unroll
        for (int n = 0; n < 4; ++n) {
            bf[n][0] = *(const bf16x8*)(Bb + brow0 + n * 1024 + koff0);
            bf[n][1] = *(const bf16x8*)(Bb + brow0 + n * 1024 + koff1);
        }
        READ_A(0)
        MFMA_PH(0)
        READ_A(1)
        MFMA_PH(1)

        // ---- mid: retire A half 1 (cvt+write), issue A half 2 ----
        if (pf) {
            A_WRITE(0, An) A_WRITE(1, An)
            A_LOAD(2, kc) A_LOAD(3, kc)
        }

        // ---- compute phases 2-3 ----
        READ_A(2)
        MFMA_PH(2)
        READ_A(3)
        MFMA_PH(3)

        // ---- end: retire A half 2; boundary handoff ----
        if (pf) { A_WRITE(2, An) A_WRITE(3, An) }
        __syncthreads();   // lgkm (A writes visible) + vmcnt (B DMA resident)
    }
#undef MFMA_PH
#undef READ_A
#undef A_WRITE
#undef A_LOAD
#undef STG_B

    // ---- epilogue: C/D layout col=lane&15, row=(lane>>4)*4+reg ----
    const int cr = (ln >> 4) * 4;
    const int cc = ln & 15;
#pragma unroll
    for (int fm = 0; fm < 8; ++fm) {
#pragma unroll
        for (int rr = 0; rr < 4; ++rr) {
            int row = m0 + wr * 128 + fm * 16 + cr + rr;
            float* p = C + (size_t)row * N + n0 + wc * 64 + cc;
#pragma unroll
            for (int fn = 0; fn < 4; ++fn)
                p[fn * 16] = acc[fm][fn][rr];
        }
    }
}

// ---------------- launch ----------------

extern "C" void kernel_launch(void* const* d_in, const int* in_sizes, int n_in,
                              void* d_out, int out_size, void* d_ws, size_t ws_size,
                              hipStream_t stream) {
    const float* x  = (const float*)d_in[0];
    const float* c0 = (const float*)d_in[1];
    const float* c1 = (const float*)d_in[2];
    const float* c2 = (const float*)d_in[3];
    float* out = (float*)d_out;

    const int K = 1024;             // input dim
    const int N = 4096;             // OUT_DIM * SUP
    const int M = in_sizes[0] / K;  // tokens = B*S

    u16* Wt = (u16*)d_ws;           // N*K bf16 fused weight

    prep_w_kernel<<<512, 256, 0, stream>>>(c0, c1, c2, Wt);
    gemm256_kernel<<<(N / 256) * (M / 256), 512, 0, stream>>>(x, Wt, out, M, N, K);
}

// Round 15
// 58.329 us; speedup vs baseline: 1.0114x; 1.0114x over previous
//
#include <hip/hip_runtime.h>
#include <stdint.h>

typedef unsigned short u16;
typedef unsigned int u32;
typedef __bf16 bf16x8 __attribute__((ext_vector_type(8)));
typedef float f32x4 __attribute__((ext_vector_type(4)));

#define MFMA16 __builtin_amdgcn_mfma_f32_16x16x32_bf16

// ---------------- helpers ----------------

__device__ __forceinline__ u16 f2bf(float f) {
    u32 u = __builtin_bit_cast(u32, f);
    u32 r = (u + 0x7FFFu + ((u >> 16) & 1u)) >> 16;
    return (u16)r;
}

__device__ __forceinline__ void gload_lds16(const u16* g, u16* l) {
    __builtin_amdgcn_global_load_lds(
        (const __attribute__((address_space(1))) void*)g,
        (__attribute__((address_space(3))) void*)l,
        16, 0, 0);
}

// ================= kernel 1: merged conv_x + prep_w =================
// blocks [0, convBlocks): x fp32 -> bf16 (8 elems/thread).
// blocks [convBlocks, convBlocks+512): fused TT weight precompute ->
//   Wt[o*4+s][i] (bf16 [4096][1024]) = sum_{q,r} c0[b,w,q,s]*c1[q,c,x,r,s]*c2[r,d,y,s]
//   i=(b*128+c*8+d), o=(w*128+x*8+y); 512 blocks = (bc=128)x(part=4).

__global__ __launch_bounds__(256) void pre_kernel(const float* __restrict__ x,
                                                  const float* __restrict__ c0,
                                                  const float* __restrict__ c1,
                                                  const float* __restrict__ c2,
                                                  u16* __restrict__ xb,
                                                  u16* __restrict__ Wt,
                                                  int convBlocks, int nElem) {
    __shared__ float smem[10496];   // 41 KB: c0(256) c1(4096) c2(2048) w1(4096)
    const int t = threadIdx.x;

    if ((int)blockIdx.x < convBlocks) {
        int i = (blockIdx.x * 256 + t) * 8;
        if (i + 8 > nElem) return;
        float4 a = *reinterpret_cast<const float4*>(x + i);
        float4 b = *reinterpret_cast<const float4*>(x + i + 4);
        uint4 pk;
        pk.x = (u32)f2bf(a.x) | ((u32)f2bf(a.y) << 16);
        pk.y = (u32)f2bf(a.z) | ((u32)f2bf(a.w) << 16);
        pk.z = (u32)f2bf(b.x) | ((u32)f2bf(b.y) << 16);
        pk.w = (u32)f2bf(b.z) | ((u32)f2bf(b.w) << 16);
        *reinterpret_cast<uint4*>(xb + i) = pk;
        return;
    }

    float* l_c0 = smem;           // [w][q][s]     (slice at fixed b)
    float* l_c1 = smem + 256;     // [q][x][r][s]  (slice at fixed c)
    float* l_c2 = smem + 4352;    // [r][d][y][s]  (full)
    float* l_w1 = smem + 6400;    // [w][x][r][s]

    const int bid = blockIdx.x - convBlocks;
    const int bc = bid >> 2;      // 0..127
    const int part = bid & 3;     // 0..3 : w-pair {2p, 2p+1}
    const int b = bc >> 4, c = bc & 15;

    l_c0[t] = c0[b * 256 + t];
#pragma unroll
    for (int q = 0; q < 8; ++q) {
        l_c1[q * 512 + t]       = c1[(q * 16 + c) * 512 + t];
        l_c1[q * 512 + t + 256] = c1[(q * 16 + c) * 512 + t + 256];
    }
#pragma unroll
    for (int j = 0; j < 8; ++j) l_c2[t + 256 * j] = c2[t + 256 * j];
    __syncthreads();

    // W1[w][x][r][s] = sum_q c0[w,q,s] * c1[q,x,r,s]   (only w in {2p,2p+1})
#pragma unroll
    for (int j = 0; j < 4; ++j) {
        int idx = t + 256 * (part * 4 + j);   // ((w*16+x)*8+r)*4+s
        int s = idx & 3;
        int r = (idx >> 2) & 7;
        int xx = (idx >> 5) & 15;
        int w = idx >> 9;
        float acc = 0.f;
#pragma unroll
        for (int q = 0; q < 8; ++q)
            acc += l_c0[(w * 8 + q) * 4 + s] * l_c1[q * 512 + (xx * 8 + r) * 4 + s];
        l_w1[idx] = acc;
    }
    __syncthreads();

    // Wt[(o*4+s)][b*128+c*8+d] = sum_r W1[w,x,r,s] * c2[r,d,y,s]
#pragma unroll
    for (int j = 0; j < 4; ++j) {
        int idx = t + 256 * (part * 4 + j);   // ((w*16+x)*8+y)*4+s == o*4+s
        int s = idx & 3;
        int y = (idx >> 2) & 7;
        int xx = (idx >> 5) & 15;
        int w = idx >> 9;
        float acc[8] = {0.f, 0.f, 0.f, 0.f, 0.f, 0.f, 0.f, 0.f};
#pragma unroll
        for (int r = 0; r < 8; ++r) {
            float w1 = l_w1[((w * 16 + xx) * 8 + r) * 4 + s];
#pragma unroll
            for (int d = 0; d < 8; ++d)
                acc[d] += w1 * l_c2[((r * 8 + d) * 8 + y) * 4 + s];
        }
        uint4 pk;
        pk.x = (u32)f2bf(acc[0]) | ((u32)f2bf(acc[1]) << 16);
        pk.y = (u32)f2bf(acc[2]) | ((u32)f2bf(acc[3]) << 16);
        pk.z = (u32)f2bf(acc[4]) | ((u32)f2bf(acc[5]) << 16);
        pk.w = (u32)f2bf(acc[6]) | ((u32)f2bf(acc[7]) << 16);
        *reinterpret_cast<uint4*>(&Wt[(size_t)idx * 1024 + b * 128 + c * 8]) = pk;
    }
}

// ========== kernel 2: 256x256 8-phase GEMM, COUNTED vmcnt (best: R12) ==========
// C[M][N] = A[M][K] * B[N][K]^T.  A = xb, B = Wt (both bf16 [4096][1024]).
// 512 threads = 8 waves (2M x 4N); per-wave 128x64 = acc[8][4] 16x16 frags.
// K-tile BK=64 (rows are 128 B); 2 dbuf slots; LDS 128 KiB.
// Measured (R12): 44.6 us, MfmaUtil 28.7%, conflicts 0, FETCH 24.6 MB.
// This is the m97-structure-family ceiling for this shape: K-loop ~34 us
// (~1000 TF internal) + compulsory 67 MB fp32 C-write ~10.6 us.

#define SLOT_U16 16384   // one slot of A (or B): 256 rows * 64 u16 = 32 KB

#define BAR() __builtin_amdgcn_s_barrier()

__global__ __launch_bounds__(512, 2) void gemm256_kernel(const u16* __restrict__ A,
                                                         const u16* __restrict__ B,
                                                         float* __restrict__ C,
                                                         int M, int N, int K) {
    __shared__ u16 As[2 * SLOT_U16];  // 64 KB
    __shared__ u16 Bs[2 * SLOT_U16];  // 64 KB

    const int t   = threadIdx.x;
    const int ln  = t & 63;
    const int wid = t >> 6;          // 0..7
    const int wr  = wid >> 2;        // 0..1 -> M offset wr*128
    const int wc  = wid & 3;         // 0..3 -> N offset wc*64

    // ---- XCD-aware bijective block swizzle (grid 256 = 16 x 16) ----
    const int bid = blockIdx.x;
    const int xcd = bid & 7;
    const int r8  = bid >> 3;            // 0..31
    const int bx  = (xcd & 1) * 8 + (r8 & 7);
    const int by  = (xcd >> 1) * 4 + (r8 >> 3);
    const int m0  = by * 256;
    const int n0  = bx * 256;
    const int NT  = K >> 6;          // 16 K-tiles

    // ---- fragment addressing: row = base + fm*16 + (ln&15); row&7 = ln&7 ----
    const int frow  = ln & 15;
    const int koff0 = (((ln >> 4)    ) ^ (ln & 7)) * 8;   // kk=0 chunk (u16)
    const int koff1 = (((ln >> 4) + 4) ^ (ln & 7)) * 8;   // kk=1 chunk
    const int arow0 = (wr * 128 + frow) * 64;             // + fm*1024
    const int brow0 = (wc * 64  + frow) * 64;             // + fn*1024

    // ---- staging: one load = 64 rows x 8 chunks; thread t -> row t>>3,
    //      phys chunk t&7 -> logical chunk (t&7)^((t>>3)&7).
    const int srow = t >> 3;
    const int scol = ((t & 7) ^ (srow & 7)) * 8;
    const u16* Asrc = A + (size_t)(m0 + srow) * K + scol;
    const u16* Bsrc = B + (size_t)(n0 + srow) * K + scol;

    f32x4 acc[8][4] = {};

#define STG(SRC, DST, H, L, KC)                                              \
    gload_lds16(SRC + (size_t)((H) * 128 + (L) * 64) * K + (KC),             \
                DST + (H) * 8192 + (L) * 4096 + t * 8);

#define READ_A(PH)                                                           \
    a0k0 = *(const bf16x8*)(Ab + arow0 + (2 * (PH)) * 1024 + koff0);         \
    a0k1 = *(const bf16x8*)(Ab + arow0 + (2 * (PH)) * 1024 + koff1);         \
    a1k0 = *(const bf16x8*)(Ab + arow0 + (2 * (PH) + 1) * 1024 + koff0);     \
    a1k1 = *(const bf16x8*)(Ab + arow0 + (2 * (PH) + 1) * 1024 + koff1);

#define MFMA_PH(PH)                                                          \
    _Pragma("unroll")                                                        \
    for (int n = 0; n < 4; ++n) {                                            \
        acc[2*(PH)][n]   = MFMA16(a0k0, bf[n][0], acc[2*(PH)][n],   0,0,0);  \
        acc[2*(PH)][n]   = MFMA16(a0k1, bf[n][1], acc[2*(PH)][n],   0,0,0);  \
        acc[2*(PH)+1][n] = MFMA16(a1k0, bf[n][0], acc[2*(PH)+1][n], 0,0,0);  \
        acc[2*(PH)+1][n] = MFMA16(a1k1, bf[n][1], acc[2*(PH)+1][n], 0,0,0);  \
    }

    // ---- prologue: stage tile 0 fully; drain; rendezvous ----
    STG(Bsrc, Bs, 0, 0, 0) STG(Bsrc, Bs, 0, 1, 0)
    STG(Bsrc, Bs, 1, 0, 0) STG(Bsrc, Bs, 1, 1, 0)
    STG(Asrc, As, 0, 0, 0) STG(Asrc, As, 1, 0, 0)
    STG(Asrc, As, 0, 1, 0) STG(Asrc, As, 1, 1, 0)
    asm volatile("s_waitcnt vmcnt(0)" ::: "memory");
    BAR();

    for (int kt = 0; kt < NT; ++kt) {
        const u16* Ab = As + (kt & 1) * SLOT_U16;
        const u16* Bb = Bs + (kt & 1) * SLOT_U16;
        u16* An = As + ((kt + 1) & 1) * SLOT_U16;
        u16* Bn = Bs + ((kt + 1) & 1) * SLOT_U16;
        const bool pf = (kt + 1) < NT;
        const int kc = (kt + 1) * 64;

        bf16x8 bf[4][2];
        bf16x8 a0k0, a0k1, a1k0, a1k1;

        // ======== phase 0: all B frags + A fm0,1 ; stage B-h0 ========
#pragma unroll
        for (int n = 0; n < 4; ++n) {
            bf[n][0] = *(const bf16x8*)(Bb + brow0 + n * 1024 + koff0);
            bf[n][1] = *(const bf16x8*)(Bb + brow0 + n * 1024 + koff1);
        }
        READ_A(0)
        if (pf) { STG(Bsrc, Bn, 0, 0, kc) STG(Bsrc, Bn, 0, 1, kc) }
        BAR();
        __builtin_amdgcn_s_setprio(1);
        MFMA_PH(0)
        __builtin_amdgcn_s_setprio(0);
        BAR();

        // ======== phase 1: A fm2,3 ; stage B-h1 ; wait own A-L1 ========
        READ_A(1)
        if (pf) { STG(Bsrc, Bn, 1, 0, kc) STG(Bsrc, Bn, 1, 1, kc) }
        BAR();
        __builtin_amdgcn_s_setprio(1);
        MFMA_PH(1)
        __builtin_amdgcn_s_setprio(0);
        if (pf) { asm volatile("s_waitcnt vmcnt(4)" ::: "memory"); }
        else    { asm volatile("s_waitcnt vmcnt(0)" ::: "memory"); }
        BAR();

        // ======== phase 2: A fm4,5 ; stage A L0 pair ========
        READ_A(2)
        if (pf) { STG(Asrc, An, 0, 0, kc) STG(Asrc, An, 1, 0, kc) }
        BAR();
        __builtin_amdgcn_s_setprio(1);
        MFMA_PH(2)
        __builtin_amdgcn_s_setprio(0);
        BAR();

        // ======== phase 3: A fm6,7 ; stage A L1 pair ; boundary vmcnt(2) ========
        READ_A(3)
        if (pf) { STG(Asrc, An, 0, 1, kc) STG(Asrc, An, 1, 1, kc) }
        BAR();
        __builtin_amdgcn_s_setprio(1);
        MFMA_PH(3)
        __builtin_amdgcn_s_setprio(0);
        if (pf) { asm volatile("s_waitcnt vmcnt(2)" ::: "memory"); }
        BAR();
    }
#undef MFMA_PH
#undef READ_A
#undef STG

    // ---- epilogue: C/D layout col=lane&15, row=(lane>>4)*4+reg ----
    const int cr = (ln >> 4) * 4;
    const int cc = ln & 15;
#pragma unroll
    for (int fm = 0; fm < 8; ++fm) {
#pragma unroll
        for (int rr = 0; rr < 4; ++rr) {
            int row = m0 + wr * 128 + fm * 16 + cr + rr;
            float* p = C + (size_t)row * N + n0 + wc * 64 + cc;
#pragma unroll
            for (int fn = 0; fn < 4; ++fn)
                p[fn * 16] = acc[fm][fn][rr];
        }
    }
}

// ---------------- launch ----------------

extern "C" void kernel_launch(void* const* d_in, const int* in_sizes, int n_in,
                              void* d_out, int out_size, void* d_ws, size_t ws_size,
                              hipStream_t stream) {
    const float* x  = (const float*)d_in[0];
    const float* c0 = (const float*)d_in[1];
    const float* c1 = (const float*)d_in[2];
    const float* c2 = (const float*)d_in[3];
    float* out = (float*)d_out;

    const int K = 1024;             // input dim
    const int N = 4096;             // OUT_DIM * SUP
    const int M = in_sizes[0] / K;  // tokens = B*S

    u16* xb = (u16*)d_ws;                        // M*K bf16
    u16* Wt = (u16*)d_ws + (size_t)M * K;        // N*K bf16

    const int convBlocks = (M * K) / (256 * 8);
    pre_kernel<<<convBlocks + 512, 256, 0, stream>>>(x, c0, c1, c2, xb, Wt,
                                                     convBlocks, M * K);

    gemm256_kernel<<<(N / 256) * (M / 256), 512, 0, stream>>>(xb, Wt, out, M, N, K);
}